// Round 5
// baseline (112.773 us; speedup 1.0000x reference)
//
#include <hip/hip_runtime.h>

// Fused iterated 3x3 median blur (edge-replicate), up to 9 iterations in LDS.
// 64x64 output tile; LDS tile = 82 rows x 88 cols (28.9 KB, 5 blocks/CU).
//   rows: gy in [y0-9,  y0+72]  (halo 9 both sides)
//   cols: gx in [x0-12, x0+75]  (halo 12 left / 12 right)
// Column stride 88 => bank offset per 5-row group = 5*88 mod 32 = 24, giving
// EXACTLY 2 lanes/bank for the compute-loop LDS ops (2-way = free), and
// 88 = 22*float4 with 16B-aligned global base for x-interior tiles.
// Each thread computes a contiguous 5x5 patch of region rows[1,80]xcols[4,83]
// (6400 = 256*25). Valid-after-k: rows [k,81-k], cols [3+k,84-k]; after 9
// iters = rows [9,72] x cols [12,75] = exactly the output tile. Replicate
// padding maintained by per-iteration pad refresh on image-edge tiles.

#define ROWS 82
#define COLS 88
#define OW 64
#define RAD 9           // row halo
#define CL 12           // left/right col halo
#define NT 256

__device__ __forceinline__ float min3f(float a, float b, float c) { return fminf(fminf(a, b), c); }
__device__ __forceinline__ float max3f(float a, float b, float c) { return fmaxf(fmaxf(a, b), c); }
__device__ __forceinline__ float med3f(float a, float b, float c) { return __builtin_amdgcn_fmed3f(a, b, c); }

__global__ __launch_bounds__(NT) void median_fused_kernel(
    const float* __restrict__ src, float* __restrict__ dst,
    const int* __restrict__ t)
{
    __shared__ float buf[ROWS * COLS];

    const int b   = blockIdx.y;
    const int y0  = (blockIdx.x >> 3) * OW;   // 8x8 tiles of 64
    const int x0  = (blockIdx.x & 7) * OW;
    const int tid = threadIdx.x;
    const float* img  = src + (b << 18);
    float*       outb = dst + (b << 18);

    int T = t[b];
    T = min(max(T, 0), 9);

    const int sr = tid >> 4;            // store: 16 row groups x 4
    const int sc = (tid & 15) << 2;     // store: 16 x float4

    if (T == 0) {                       // straight vector copy, no LDS
        #pragma unroll
        for (int rr = 0; rr < 4; ++rr) {
            int gy = y0 + sr + rr * 16;
            *(float4*)&outb[(gy << 9) + x0 + sc] =
                *(const float4*)&img[(gy << 9) + x0 + sc];
        }
        return;
    }

    // ---- load halo tile (rows clamped; cols clamped only on x-edge tiles) ----
    if (x0 >= OW && x0 <= 512 - 2 * OW) {
        // x-interior: aligned float4 loads (gx base = x0-12, 16B aligned)
        for (int i = tid; i < ROWS * (COLS / 4); i += NT) {
            int r = i / (COLS / 4), c4 = i - r * (COLS / 4);
            int gy = min(max(y0 - RAD + r, 0), 511);
            float4 v = *(const float4*)&img[(gy << 9) + (x0 - CL) + (c4 << 2)];
            *(float4*)&buf[r * COLS + (c4 << 2)] = v;
        }
    } else {
        for (int i = tid; i < ROWS * COLS; i += NT) {
            int r = i / COLS, c = i - r * COLS;
            int gy = min(max(y0 - RAD + r, 0), 511);
            int gx = min(max(x0 - CL + c, 0), 511);
            buf[r * COLS + c] = img[(gy << 9) + gx];
        }
    }

    // image range in tile coords: (u,v) -> image (y0+u-RAD, x0+v-CL)
    const int uLo = RAD - y0, uHi = 511 + RAD - y0;
    const int vLo = CL - x0,  vHi = 511 + CL - x0;
    const int uLoC = max(uLo, 0), uHiC = min(uHi, ROWS - 1);
    const int vLoC = max(vLo, 0), vHiC = min(vHi, COLS - 1);
    const int topN = max(uLo, 0);
    const int botN = (uHi <= ROWS - 2) ? (min(ROWS - 1, uHi + RAD) - uHi) : 0;
    const int lftN = max(vLo, 0);
    const int rgtN = (vHi <= COLS - 2) ? (min(COLS - 1, vHi + CL) - vHi) : 0;
    const bool hasPad = (topN | botN | lftN | rgtN) != 0;   // block-uniform

    const int ptx = tid & 15;           // 16 col groups x 5
    const int pty = tid >> 4;           // 16 row groups x 5 (contiguous)
    const int ub  = 1 + 5 * pty;        // compute rows [1,80]
    const int vb  = 4 + 5 * ptx;        // compute cols [4,83]
    float* wrow = &buf[ub * COLS + vb];

    __syncthreads();

    for (int k = 0; k < T; ++k) {
        float A[7], Br[7], C[7], stage[25];
        const float* p = &buf[(ub - 1) * COLS + (vb - 1)];
        #pragma unroll
        for (int j = 0; j < 7; ++j) A[j] = p[j];
        p += COLS;
        #pragma unroll
        for (int j = 0; j < 7; ++j) Br[j] = p[j];
        #pragma unroll
        for (int i = 0; i < 5; ++i) {
            p += COLS;
            #pragma unroll
            for (int j = 0; j < 7; ++j) C[j] = p[j];
            float lo[7], mi[7], hi[7];
            #pragma unroll
            for (int j = 0; j < 7; ++j) {
                lo[j] = min3f(A[j], Br[j], C[j]);
                mi[j] = med3f(A[j], Br[j], C[j]);
                hi[j] = max3f(A[j], Br[j], C[j]);
            }
            #pragma unroll
            for (int j = 0; j < 5; ++j)
                stage[i * 5 + j] = med3f(max3f(lo[j], lo[j+1], lo[j+2]),
                                         med3f(mi[j], mi[j+1], mi[j+2]),
                                         min3f(hi[j], hi[j+1], hi[j+2]));
            #pragma unroll
            for (int j = 0; j < 7; ++j) { A[j] = Br[j]; Br[j] = C[j]; }
        }
        __syncthreads();                // reads of old state done
        #pragma unroll
        for (int i = 0; i < 5; ++i)
            #pragma unroll
            for (int j = 0; j < 5; ++j)
                wrow[i * COLS + j] = stage[i * 5 + j];
        __syncthreads();                // new state visible
        if (hasPad) {
            // refresh pad strips from clamped in-image cells (sources in-image
            // -> never a destination -> race-free; corners written twice with
            // identical values)
            const int nh = (topN + botN) * COLS;
            for (int i = tid; i < nh; i += NT) {
                int r = i / COLS, c = i - r * COLS;
                int u  = (r < topN) ? r : (uHi + 1 + r - topN);
                int cu = min(max(u, uLoC), uHiC);
                int cv = min(max(c, vLoC), vHiC);
                buf[u * COLS + c] = buf[cu * COLS + cv];
            }
            const int nv = (lftN + rgtN) * ROWS;
            for (int i = tid; i < nv; i += NT) {
                int ci = i / ROWS, r = i - ci * ROWS;
                int v  = (ci < lftN) ? ci : (vHi + 1 + ci - lftN);
                int cu = min(max(r, uLoC), uHiC);
                int cv = min(max(v, vLoC), vHiC);
                buf[r * COLS + v] = buf[cu * COLS + cv];
            }
            __syncthreads();
        }
    }

    // ---- store 64x64 output tile, b128 LDS reads + float4 global stores ----
    #pragma unroll
    for (int rr = 0; rr < 4; ++rr) {
        int row = sr + rr * 16;
        const float* s = &buf[(row + RAD) * COLS + CL + sc];
        float4 v = { s[0], s[1], s[2], s[3] };
        *(float4*)&outb[((y0 + row) << 9) + x0 + sc] = v;
    }
}

extern "C" void kernel_launch(void* const* d_in, const int* in_sizes, int n_in,
                              void* d_out, int out_size, void* d_ws, size_t ws_size,
                              hipStream_t stream) {
    const float* x   = (const float*)d_in[0];
    const int*   t   = (const int*)d_in[1];
    float*       out = (float*)d_out;

    dim3 block(NT);
    dim3 grid(64, 32);   // 8x8 full tiles x 32 batches
    median_fused_kernel<<<grid, block, 0, stream>>>(x, out, t);
}

// Round 6
// 107.913 us; speedup vs baseline: 1.0450x; 1.0450x over previous
//
#include <hip/hip_runtime.h>

// Fused iterated 3x3 median blur (edge-replicate), up to 9 iterations in LDS.
// 64x64 output tile + 9 halo = 82x82 LDS (26.9 KB -> 6 blocks/CU).
// Each thread owns a contiguous 5x5 patch of compute region [1,80]^2
// (6400 = 256*25). Valid-after-k (interior side) = [k, 81-k]; after 9 iters
// = [9,72] = exactly the output tile. Image-edge replicate padding is
// maintained by a 1-wide pad ring FOLDED INTO THE WRITE PHASE: the thread
// owning the edge-adjacent cell writes its value a second time into the pad
// cell (same thread -> race-free, no extra barrier, no refresh loops).

#define TD 82
#define OW 64
#define RAD 9
#define NT 256

__device__ __forceinline__ float min3f(float a, float b, float c) { return fminf(fminf(a, b), c); }
__device__ __forceinline__ float max3f(float a, float b, float c) { return fmaxf(fmaxf(a, b), c); }
__device__ __forceinline__ float med3f(float a, float b, float c) { return __builtin_amdgcn_fmed3f(a, b, c); }

__global__ __launch_bounds__(NT, 6) void median_fused_kernel(
    const float* __restrict__ src, float* __restrict__ dst,
    const int* __restrict__ t)
{
    __shared__ float buf[TD * TD];

    const int b   = blockIdx.y;
    const int y0  = (blockIdx.x >> 3) * OW;   // 8x8 tiles of 64
    const int x0  = (blockIdx.x & 7) * OW;
    const int tid = threadIdx.x;
    const float* img  = src + (b << 18);
    float*       outb = dst + (b << 18);

    int T = t[b];
    T = min(max(T, 0), 9);

    const int sr = tid >> 4;            // store: 16 row groups x 4
    const int sc = (tid & 15) << 2;     // store: 16 x float4

    if (T == 0) {                       // straight vector copy, no LDS
        #pragma unroll
        for (int rr = 0; rr < 4; ++rr) {
            int gy = y0 + sr + rr * 16;
            *(float4*)&outb[(gy << 9) + x0 + sc] =
                *(const float4*)&img[(gy << 9) + x0 + sc];
        }
        return;
    }

    // ---- load 82x82 halo tile, clamped (= replicate-padded image X~_0) ----
    for (int i = tid; i < TD * TD; i += NT) {
        int r = i / TD, c = i - r * TD;
        int gy = min(max(y0 - RAD + r, 0), 511);
        int gx = min(max(x0 - RAD + c, 0), 511);
        buf[i] = img[(gy << 9) + gx];
    }

    // image-edge flags (block-uniform): which sides have replicate pads
    const bool topE = (y0 == 0),   botE = (y0 == 512 - OW);
    const bool lftE = (x0 == 0),   rgtE = (x0 == 512 - OW);

    const int ptx = tid & 15;           // 16 col groups x 5
    const int pty = tid >> 4;           // 16 row groups x 5 (contiguous)
    const int ub  = 1 + 5 * pty;        // patch rows [ub, ub+4]
    const int vb  = 1 + 5 * ptx;        // patch cols [vb, vb+4]
    float* wrow = &buf[ub * TD + vb];

    // pad-writer roles: cell u=9 (image row 0) lives in patch pty==1 at i=3;
    // cell u=72 (row 511) in pty==14 at i=1; same for columns.
    const bool padTop = topE && (pty == 1);    // write stage[15+j] -> (8,  vb+j)
    const bool padBot = botE && (pty == 14);   // write stage[ 5+j] -> (73, vb+j)
    const bool padLft = lftE && (ptx == 1);    // write stage[i*5+3] -> (ub+i, 8)
    const bool padRgt = rgtE && (ptx == 14);   // write stage[i*5+1] -> (ub+i, 73)

    __syncthreads();

    for (int k = 0; k < T; ++k) {
        float A[7], Br[7], C[7], stage[25];
        const float* p = &buf[(ub - 1) * TD + (vb - 1)];
        #pragma unroll
        for (int j = 0; j < 7; ++j) A[j] = p[j];
        p += TD;
        #pragma unroll
        for (int j = 0; j < 7; ++j) Br[j] = p[j];
        #pragma unroll
        for (int i = 0; i < 5; ++i) {
            p += TD;
            #pragma unroll
            for (int j = 0; j < 7; ++j) C[j] = p[j];
            float lo[7], mi[7], hi[7];
            #pragma unroll
            for (int j = 0; j < 7; ++j) {
                lo[j] = min3f(A[j], Br[j], C[j]);
                mi[j] = med3f(A[j], Br[j], C[j]);
                hi[j] = max3f(A[j], Br[j], C[j]);
            }
            #pragma unroll
            for (int j = 0; j < 5; ++j)
                stage[i * 5 + j] = med3f(max3f(lo[j], lo[j+1], lo[j+2]),
                                         med3f(mi[j], mi[j+1], mi[j+2]),
                                         min3f(hi[j], hi[j+1], hi[j+2]));
            #pragma unroll
            for (int j = 0; j < 7; ++j) { A[j] = Br[j]; Br[j] = C[j]; }
        }
        __syncthreads();                // reads of old state done
        #pragma unroll
        for (int i = 0; i < 5; ++i)
            #pragma unroll
            for (int j = 0; j < 5; ++j)
                wrow[i * TD + j] = stage[i * 5 + j];
        // folded 1-wide replicate-pad refresh (same-thread double writes)
        if (padTop) {
            #pragma unroll
            for (int j = 0; j < 5; ++j) buf[8 * TD + vb + j] = stage[15 + j];
            if (padLft) buf[8 * TD + 8]  = stage[18];   // (8,8)  <- new(9,9)
            if (padRgt) buf[8 * TD + 73] = stage[16];   // (8,73) <- new(9,72)
        }
        if (padBot) {
            #pragma unroll
            for (int j = 0; j < 5; ++j) buf[73 * TD + vb + j] = stage[5 + j];
            if (padLft) buf[73 * TD + 8]  = stage[8];   // (73,8)  <- new(72,9)
            if (padRgt) buf[73 * TD + 73] = stage[6];   // (73,73) <- new(72,72)
        }
        if (padLft) {
            #pragma unroll
            for (int i = 0; i < 5; ++i) buf[(ub + i) * TD + 8] = stage[i * 5 + 3];
        }
        if (padRgt) {
            #pragma unroll
            for (int i = 0; i < 5; ++i) buf[(ub + i) * TD + 73] = stage[i * 5 + 1];
        }
        __syncthreads();                // new state (incl. pads) visible
    }

    // ---- store 64x64 output tile, float4 global stores ----
    #pragma unroll
    for (int rr = 0; rr < 4; ++rr) {
        int row = sr + rr * 16;
        const float* s = &buf[(row + RAD) * TD + RAD + sc];
        float4 v = { s[0], s[1], s[2], s[3] };
        *(float4*)&outb[((y0 + row) << 9) + x0 + sc] = v;
    }
}

extern "C" void kernel_launch(void* const* d_in, const int* in_sizes, int n_in,
                              void* d_out, int out_size, void* d_ws, size_t ws_size,
                              hipStream_t stream) {
    const float* x   = (const float*)d_in[0];
    const int*   t   = (const int*)d_in[1];
    float*       out = (float*)d_out;

    dim3 block(NT);
    dim3 grid(64, 32);   // 8x8 full tiles x 32 batches
    median_fused_kernel<<<grid, block, 0, stream>>>(x, out, t);
}

// Round 7
// 104.481 us; speedup vs baseline: 1.0794x; 1.0329x over previous
//
#include <hip/hip_runtime.h>

// Fused iterated 3x3 median blur (edge-replicate), up to 9 iterations.
// 64x64 output tile + 9 halo = 82x82 LDS (26.9 KB -> 6 blocks/CU).
// Each thread owns a contiguous 5x5 patch of compute region [1,80]^2 and
// KEEPS IT IN REGISTERS across iterations (stage[25]). Per iteration only
// the 24-cell halo ring is read from LDS and the 16-cell patch ring written
// back (interior 3x3 is never read by other threads). Final iteration writes
// all 25 so the vectorized store path reads LDS. Image-edge replicate pads
// are maintained as REGISTER fixups in the pad-owning threads (row fix then
// col fix -> corners exact); ring writes then carry pad values to LDS.

#define TD 82
#define OW 64
#define RAD 9
#define NT 256

__device__ __forceinline__ float min3f(float a, float b, float c) { return fminf(fminf(a, b), c); }
__device__ __forceinline__ float max3f(float a, float b, float c) { return fmaxf(fmaxf(a, b), c); }
__device__ __forceinline__ float med3f(float a, float b, float c) { return __builtin_amdgcn_fmed3f(a, b, c); }

__global__ __launch_bounds__(NT) void median_fused_kernel(
    const float* __restrict__ src, float* __restrict__ dst,
    const int* __restrict__ t)
{
    __shared__ float buf[TD * TD];

    const int b   = blockIdx.y;
    const int y0  = (blockIdx.x >> 3) * OW;   // 8x8 tiles of 64
    const int x0  = (blockIdx.x & 7) * OW;
    const int tid = threadIdx.x;
    const float* img  = src + (b << 18);
    float*       outb = dst + (b << 18);

    int T = t[b];
    T = min(max(T, 0), 9);

    const int sr = tid >> 4;            // store: 16 row groups x 4
    const int sc = (tid & 15) << 2;     // store: 16 x float4

    if (T == 0) {                       // straight vector copy, no LDS
        #pragma unroll
        for (int rr = 0; rr < 4; ++rr) {
            int gy = y0 + sr + rr * 16;
            *(float4*)&outb[(gy << 9) + x0 + sc] =
                *(const float4*)&img[(gy << 9) + x0 + sc];
        }
        return;
    }

    // ---- load 82x82 halo tile, clamped (= replicate-padded image) ----
    for (int i = tid; i < TD * TD; i += NT) {
        int r = i / TD, c = i - r * TD;
        int gy = min(max(y0 - RAD + r, 0), 511);
        int gx = min(max(x0 - RAD + c, 0), 511);
        buf[i] = img[(gy << 9) + gx];
    }

    const bool topE = (y0 == 0), botE = (y0 == 512 - OW);
    const bool lftE = (x0 == 0), rgtE = (x0 == 512 - OW);

    const int ptx = tid & 15;           // 16 col groups x 5
    const int pty = tid >> 4;           // 16 row groups x 5
    const int ub  = 1 + 5 * pty;        // patch rows [ub, ub+4]
    const int vb  = 1 + 5 * ptx;        // patch cols [vb, vb+4]

    // pad-owning threads: image row 0 = tile row 9 = pty==1 patch-row i=3
    // (pad row 8 = i=2); image row 511 = tile row 72 = pty==14 i=1 (pad 73
    // = i=2). Columns symmetric.
    const bool padTop = topE && (pty == 1);
    const bool padBot = botE && (pty == 14);
    const bool padLft = lftE && (ptx == 1);
    const bool padRgt = rgtE && (ptx == 14);

    __syncthreads();

    // preload own 5x5 patch (state 0) into registers
    float stage[25];
    #pragma unroll
    for (int i = 0; i < 5; ++i)
        #pragma unroll
        for (int j = 0; j < 5; ++j)
            stage[i * 5 + j] = buf[(ub + i) * TD + vb + j];

    for (int k = 0; k < T; ++k) {
        float A[7], Br[7], C[7], ns[25];
        // window row ub-1: all 7 from LDS (neighbor ring)
        {
            const float* p = &buf[(ub - 1) * TD + (vb - 1)];
            #pragma unroll
            for (int j = 0; j < 7; ++j) A[j] = p[j];
        }
        // window row ub: edges from LDS, middle from stage row 0
        Br[0] = buf[ub * TD + (vb - 1)];
        #pragma unroll
        for (int j = 0; j < 5; ++j) Br[1 + j] = stage[j];
        Br[6] = buf[ub * TD + (vb + 5)];

        #pragma unroll
        for (int i = 0; i < 5; ++i) {
            if (i < 4) {                // rows ub+1..ub+4: edges LDS, mid regs
                C[0] = buf[(ub + 1 + i) * TD + (vb - 1)];
                #pragma unroll
                for (int j = 0; j < 5; ++j) C[1 + j] = stage[(i + 1) * 5 + j];
                C[6] = buf[(ub + 1 + i) * TD + (vb + 5)];
            } else {                    // row ub+5: all 7 from LDS
                const float* p = &buf[(ub + 5) * TD + (vb - 1)];
                #pragma unroll
                for (int j = 0; j < 7; ++j) C[j] = p[j];
            }
            float lo[7], mi[7], hi[7];
            #pragma unroll
            for (int j = 0; j < 7; ++j) {
                lo[j] = min3f(A[j], Br[j], C[j]);
                mi[j] = med3f(A[j], Br[j], C[j]);
                hi[j] = max3f(A[j], Br[j], C[j]);
            }
            #pragma unroll
            for (int j = 0; j < 5; ++j)
                ns[i * 5 + j] = med3f(max3f(lo[j], lo[j+1], lo[j+2]),
                                      med3f(mi[j], mi[j+1], mi[j+2]),
                                      min3f(hi[j], hi[j+1], hi[j+2]));
            #pragma unroll
            for (int j = 0; j < 7; ++j) { A[j] = Br[j]; Br[j] = C[j]; }
        }

        // register pad fixups (row fix first, then col fix -> corners exact)
        if (padTop) {                   // pad row 8 (i=2) <- new row 9 (i=3)
            #pragma unroll
            for (int j = 0; j < 5; ++j) ns[10 + j] = ns[15 + j];
        }
        if (padBot) {                   // pad row 73 (i=2) <- new row 72 (i=1)
            #pragma unroll
            for (int j = 0; j < 5; ++j) ns[10 + j] = ns[5 + j];
        }
        if (padLft) {                   // pad col 8 (j=2) <- new col 9 (j=3)
            #pragma unroll
            for (int i = 0; i < 5; ++i) ns[i * 5 + 2] = ns[i * 5 + 3];
        }
        if (padRgt) {                   // pad col 73 (j=2) <- new col 72 (j=1)
            #pragma unroll
            for (int i = 0; i < 5; ++i) ns[i * 5 + 2] = ns[i * 5 + 1];
        }

        __syncthreads();                // all ring reads of state k done

        if (k == T - 1) {               // final: write all 25 for store phase
            #pragma unroll
            for (int i = 0; i < 5; ++i)
                #pragma unroll
                for (int j = 0; j < 5; ++j)
                    buf[(ub + i) * TD + vb + j] = ns[i * 5 + j];
        } else {                        // write the 16-cell patch ring only
            #pragma unroll
            for (int j = 0; j < 5; ++j) buf[ub * TD + vb + j]       = ns[j];
            #pragma unroll
            for (int j = 0; j < 5; ++j) buf[(ub + 4) * TD + vb + j] = ns[20 + j];
            #pragma unroll
            for (int i = 1; i < 4; ++i) {
                buf[(ub + i) * TD + vb]     = ns[i * 5];
                buf[(ub + i) * TD + vb + 4] = ns[i * 5 + 4];
            }
        }

        #pragma unroll
        for (int m = 0; m < 25; ++m) stage[m] = ns[m];

        __syncthreads();                // new ring visible
    }

    // ---- store 64x64 output tile, float4 global stores ----
    #pragma unroll
    for (int rr = 0; rr < 4; ++rr) {
        int row = sr + rr * 16;
        const float* s = &buf[(row + RAD) * TD + RAD + sc];
        float4 v = { s[0], s[1], s[2], s[3] };
        *(float4*)&outb[((y0 + row) << 9) + x0 + sc] = v;
    }
}

extern "C" void kernel_launch(void* const* d_in, const int* in_sizes, int n_in,
                              void* d_out, int out_size, void* d_ws, size_t ws_size,
                              hipStream_t stream) {
    const float* x   = (const float*)d_in[0];
    const int*   t   = (const int*)d_in[1];
    float*       out = (float*)d_out;

    dim3 block(NT);
    dim3 grid(64, 32);   // 8x8 full tiles x 32 batches
    median_fused_kernel<<<grid, block, 0, stream>>>(x, out, t);
}